// Round 3
// baseline (87.004 us; speedup 1.0000x reference)
//
#include <hip/hip_runtime.h>
#include <math.h>

#define S_   2048
#define H_   8
#define D_   64
#define TQ   32
#define TK   160        // TQ + 128
#define HALF 64
#define PSD_W 36        // 129 offsets live diagonally; row = key, col = query (32) + pad

__global__ __launch_bounds__(256, 2)
void swa_fwd(const float* __restrict__ Q, const float* __restrict__ K,
             const float* __restrict__ V, float* __restrict__ Out)
{
    // 40960 + 23040 = 64000 B static LDS
    __shared__ float4 Ks4[TK * 16];       // swizzled K tile: row j, chunk (c ^ (j&7))
    __shared__ float  psd[TK * PSD_W];    // psd[j][sq] = p(query sq, key row j)

    const int t    = threadIdx.x;
    const int lane = t & 63;
    // wave id is uniform-in-fact; readfirstlane makes it uniform-to-the-compiler
    // so Q addressing scalarizes (s_load) and PV's V row addressing stays SGPR.
    const int w8   = __builtin_amdgcn_readfirstlane((t >> 6) << 3); // first query of this wave
    const int h    = blockIdx.y;
    const int q0   = blockIdx.x * TQ;
    const int k0   = q0 - HALF;           // global key index of local row 0

    // ---------------- stage K tile (swizzled), zero psd ----------------
    const float* Kg = K + (size_t)h * S_ * D_;
    #pragma unroll
    for (int i = 0; i < (TK * 16) / 256; ++i) {
        const int idx = t + i * 256;
        const int j = idx >> 4, c = idx & 15;
        int gk = k0 + j;
        gk = gk < 0 ? 0 : (gk > S_ - 1 ? S_ - 1 : gk);
        const float4 v = *(const float4*)(Kg + gk * D_ + c * 4);
        Ks4[(j << 4) | (c ^ (j & 7))] = v;
    }
    {
        const float4 z = make_float4(0.f, 0.f, 0.f, 0.f);
        float4* p4 = (float4*)psd;
        for (int i = t; i < (TK * PSD_W) / 4; i += 256) p4[i] = z;
    }
    __syncthreads();

    // ---------------- scores: lanes over key rows, shared across 8 queries ----------------
    const int jr0  = lane;            // round 0 key row
    const int jr1  = 64 + lane;       // round 1
    const int jr2t = 128 + lane;      // round 2 (true row)
    const int jr2  = jr2t > TK - 1 ? TK - 1 : jr2t;   // clamped for LDS read
    const int sw0  = lane & 7;        // (64+lane)&7 == lane&7
    const int sw2  = jr2 & 7;

    float acc0[8], acc1[8], acc2[8];
    #pragma unroll
    for (int q = 0; q < 8; ++q) acc0[q] = acc1[q] = acc2[q] = 0.f;

    const float* Qw = Q + ((size_t)h * S_ + q0 + w8) * D_;  // fully SGPR address

    #pragma unroll 2
    for (int c = 0; c < 16; ++c) {
        const float4 ka = Ks4[(jr0 << 4) | (c ^ sw0)];
        const float4 kb = Ks4[(jr1 << 4) | (c ^ sw0)];
        const float4 kc = Ks4[(jr2 << 4) | (c ^ sw2)];
        #pragma unroll
        for (int q = 0; q < 8; ++q) {
            const float4 qv = *(const float4*)(Qw + q * D_ + c * 4); // uniform -> s_load
            acc0[q] = fmaf(ka.x, qv.x, acc0[q]);
            acc0[q] = fmaf(ka.y, qv.y, acc0[q]);
            acc0[q] = fmaf(ka.z, qv.z, acc0[q]);
            acc0[q] = fmaf(ka.w, qv.w, acc0[q]);
            acc1[q] = fmaf(kb.x, qv.x, acc1[q]);
            acc1[q] = fmaf(kb.y, qv.y, acc1[q]);
            acc1[q] = fmaf(kb.z, qv.z, acc1[q]);
            acc1[q] = fmaf(kb.w, qv.w, acc1[q]);
            acc2[q] = fmaf(kc.x, qv.x, acc2[q]);
            acc2[q] = fmaf(kc.y, qv.y, acc2[q]);
            acc2[q] = fmaf(kc.z, qv.z, acc2[q]);
            acc2[q] = fmaf(kc.w, qv.w, acc2[q]);
        }
    }

    // ---------------- softmax (per query, wave-wide) ----------------
    const bool kv0 = (unsigned)(k0 + jr0)  < (unsigned)S_;
    const bool kv1 = (unsigned)(k0 + jr1)  < (unsigned)S_;
    const bool kv2 = (unsigned)(k0 + jr2t) < (unsigned)S_;
    const float scale = 0.125f;    // 1/sqrt(64)
    float l_[8];

    #pragma unroll
    for (int q = 0; q < 8; ++q) {
        const int sq   = w8 + q;
        const int off0 = jr0  - sq;
        const int off1 = jr1  - sq;
        const int off2 = jr2t - sq;
        const bool v0 = kv0 && ((unsigned)off0 <= 128u);
        const bool v1 = kv1 && ((unsigned)off1 <= 128u);
        const bool v2 = kv2 && ((unsigned)off2 <= 128u);
        const float x0 = v0 ? acc0[q] * scale : -1e30f;
        const float x1 = v1 ? acc1[q] * scale : -1e30f;
        const float x2 = v2 ? acc2[q] * scale : -1e30f;

        float m = fmaxf(x0, fmaxf(x1, x2));
        #pragma unroll
        for (int i = 1; i < 64; i <<= 1) m = fmaxf(m, __shfl_xor(m, i));

        const float p0 = __expf(x0 - m);
        const float p1 = __expf(x1 - m);
        const float p2 = __expf(x2 - m);

        float l = p0 + p1 + p2;
        #pragma unroll
        for (int i = 1; i < 64; i <<= 1) l += __shfl_xor(l, i);
        l_[q] = l;

        // diagonal store: psd[key_row][query]; invalid-key entries write exact 0
        if ((unsigned)off0 <= 128u) psd[jr0  * PSD_W + sq] = p0;
        if ((unsigned)off1 <= 128u) psd[jr1  * PSD_W + sq] = p1;
        if ((unsigned)off2 <= 128u) psd[jr2t * PSD_W + sq] = p2;
    }
    // psd written/read only by the owning wave's columns -> no barrier needed

    // ---------------- PV: lane = d, V rows from global (coalesced, L2) ----------------
    float accO[8];
    #pragma unroll
    for (int q = 0; q < 8; ++q) accO[q] = 0.f;

    const float* Vg = V + (size_t)h * S_ * D_ + lane;

    #pragma unroll 8
    for (int jl = 0; jl < 136; ++jl) {      // key rows w8 .. w8+135 cover off 0..128 for all 8 q
        const int jj = w8 + jl;             // SGPR
        int gk = k0 + jj;                   // SGPR
        gk = gk < 0 ? 0 : (gk > S_ - 1 ? S_ - 1 : gk);
        const float vf = Vg[gk * D_];       // SGPR base + lane*4
        const float4 pa = *(const float4*)(psd + jj * PSD_W + w8);
        const float4 pb = *(const float4*)(psd + jj * PSD_W + w8 + 4);
        accO[0] = fmaf(pa.x, vf, accO[0]);
        accO[1] = fmaf(pa.y, vf, accO[1]);
        accO[2] = fmaf(pa.z, vf, accO[2]);
        accO[3] = fmaf(pa.w, vf, accO[3]);
        accO[4] = fmaf(pb.x, vf, accO[4]);
        accO[5] = fmaf(pb.y, vf, accO[5]);
        accO[6] = fmaf(pb.z, vf, accO[6]);
        accO[7] = fmaf(pb.w, vf, accO[7]);
    }

    float* Og = Out + ((size_t)h * S_ + q0 + w8) * D_ + lane;
    #pragma unroll
    for (int q = 0; q < 8; ++q)
        Og[q * D_] = accO[q] / (l_[q] + 1e-9f);
}

extern "C" void kernel_launch(void* const* d_in, const int* in_sizes, int n_in,
                              void* d_out, int out_size, void* d_ws, size_t ws_size,
                              hipStream_t stream)
{
    const float* Q = (const float*)d_in[0];
    const float* K = (const float*)d_in[1];
    const float* V = (const float*)d_in[2];
    float* Out = (float*)d_out;
    dim3 grid(S_ / TQ, H_);
    swa_fwd<<<grid, 256, 0, stream>>>(Q, K, V, Out);
}

// Round 5
// 86.884 us; speedup vs baseline: 1.0014x; 1.0014x over previous
//
#include <hip/hip_runtime.h>
#include <math.h>

#define S_    2048
#define H_    8
#define D_    64
#define TQ    32        // queries per block
#define TK    160       // K-tile rows = TQ + 128
#define HALF  64
#define PROWS 136       // per-wave psd rows (132 used, padded to 136 for unroll-8)

__global__ __launch_bounds__(512, 4)
void swa_fwd(const float* __restrict__ Q, const float* __restrict__ K,
             const float* __restrict__ V, float* __restrict__ Out)
{
    // 40960 + 17408 = 58368 B static LDS -> 2 blocks/CU, 16 waves/CU (4/SIMD)
    __shared__ float4 Ks4[TK * 16];        // swizzled K tile: row j, chunk (c ^ (j&7))
    __shared__ float4 psd2[8 * PROWS];     // per-wave: psd2[wv*136 + rowoff] = p for the wave's 4 queries

    const int t    = threadIdx.x;
    const int lane = t & 63;
    const int wv   = t >> 6;               // wave 0..7
    const int w4   = wv << 2;              // first query (block-local) of this wave
    const int h    = blockIdx.y;
    const int q0   = blockIdx.x * TQ;
    const int k0   = q0 - HALF;            // global key index of local row 0

    // ---------------- stage K tile (swizzled), zero psd2 ----------------
    const float* Kg = K + (size_t)h * S_ * D_;
    #pragma unroll
    for (int i = 0; i < (TK * 16) / 512; ++i) {     // 5 iters
        const int idx = t + i * 512;
        const int j = idx >> 4, c = idx & 15;
        int gk = k0 + j;
        gk = gk < 0 ? 0 : (gk > S_ - 1 ? S_ - 1 : gk);
        Ks4[(j << 4) | (c ^ (j & 7))] = *(const float4*)(Kg + gk * D_ + c * 4);
    }
    {
        const float4 z = make_float4(0.f, 0.f, 0.f, 0.f);
        for (int i = t; i < 8 * PROWS; i += 512) psd2[i] = z;
    }
    __syncthreads();

    // ---------------- scores: lanes over key rows, shared across 4 queries ----------------
    // wave wv covers local rows [w4, w4+131] (3 rounds of 64 lanes, round 2 mostly masked)
    const int jr0  = w4 + lane;
    const int jr1  = w4 + 64 + lane;
    const int jr2t = w4 + 128 + lane;                  // true row
    const int jr2  = jr2t > TK - 1 ? TK - 1 : jr2t;    // clamped for LDS read

    float acc0[4], acc1[4], acc2[4];
    #pragma unroll
    for (int q = 0; q < 4; ++q) acc0[q] = acc1[q] = acc2[q] = 0.f;

    // uniform-in-fact vector loads (NOT readfirstlane: keep them on vmcnt, decoupled from ds_read)
    const float* Qw = Q + ((size_t)h * S_ + q0 + w4) * D_;

    #pragma unroll 2
    for (int c = 0; c < 16; ++c) {
        const float4 ka = Ks4[(jr0 << 4) | (c ^ (jr0 & 7))];
        const float4 kb = Ks4[(jr1 << 4) | (c ^ (jr1 & 7))];
        const float4 kc = Ks4[(jr2 << 4) | (c ^ (jr2 & 7))];
        #pragma unroll
        for (int q = 0; q < 4; ++q) {
            const float4 qv = *(const float4*)(Qw + q * D_ + c * 4);  // L1-resident broadcast
            acc0[q] = fmaf(ka.x, qv.x, acc0[q]);
            acc0[q] = fmaf(ka.y, qv.y, acc0[q]);
            acc0[q] = fmaf(ka.z, qv.z, acc0[q]);
            acc0[q] = fmaf(ka.w, qv.w, acc0[q]);
            acc1[q] = fmaf(kb.x, qv.x, acc1[q]);
            acc1[q] = fmaf(kb.y, qv.y, acc1[q]);
            acc1[q] = fmaf(kb.z, qv.z, acc1[q]);
            acc1[q] = fmaf(kb.w, qv.w, acc1[q]);
            acc2[q] = fmaf(kc.x, qv.x, acc2[q]);
            acc2[q] = fmaf(kc.y, qv.y, acc2[q]);
            acc2[q] = fmaf(kc.z, qv.z, acc2[q]);
            acc2[q] = fmaf(kc.w, qv.w, acc2[q]);
        }
    }

    // ---------------- softmax (per query, wave-wide) ----------------
    const bool kv0 = (unsigned)(k0 + jr0)  < (unsigned)S_;
    const bool kv1 = (unsigned)(k0 + jr1)  < (unsigned)S_;
    const bool kv2 = (unsigned)(k0 + jr2t) < (unsigned)S_;
    const float scale = 0.125f;    // 1/sqrt(64)
    float l_[4];

    #pragma unroll
    for (int q = 0; q < 4; ++q) {
        const int sq   = w4 + q;               // block-local query index
        const int off0 = jr0  - sq;            // in-window iff 0..128
        const int off1 = jr1  - sq;
        const int off2 = jr2t - sq;
        const bool v0 = kv0 && ((unsigned)off0 <= 128u);
        const bool v1 = kv1 && ((unsigned)off1 <= 128u);
        const bool v2 = kv2 && ((unsigned)off2 <= 128u);
        const float x0 = v0 ? acc0[q] * scale : -1e30f;
        const float x1 = v1 ? acc1[q] * scale : -1e30f;
        const float x2 = v2 ? acc2[q] * scale : -1e30f;

        float m = fmaxf(x0, fmaxf(x1, x2));
        #pragma unroll
        for (int i = 1; i < 64; i <<= 1) m = fmaxf(m, __shfl_xor(m, i));

        const float p0 = __expf(x0 - m);
        const float p1 = __expf(x1 - m);
        const float p2 = __expf(x2 - m);

        float l = p0 + p1 + p2;
        #pragma unroll
        for (int i = 1; i < 64; i <<= 1) l += __shfl_xor(l, i);
        l_[q] = l;

        // per-wave psd band: row offset = jr - w4; invalid keys write exact 0 (p underflows)
        float* pw = (float*)&psd2[wv * PROWS];
        if ((unsigned)off0 <= 128u) pw[(jr0  - w4) * 4 + q] = p0;   // rowoff 0..63
        if ((unsigned)off1 <= 128u) pw[(jr1  - w4) * 4 + q] = p1;   // rowoff 64..127
        if ((unsigned)off2 <= 128u) pw[(jr2t - w4) * 4 + q] = p2;   // rowoff 128..131 (lane<=q only)
    }
    // psd2 band is private to this wave -> no barrier needed

    // ---------------- PV: lane = d, V rows from global (coalesced, L2) ----------------
    float accO[4];
    #pragma unroll
    for (int q = 0; q < 4; ++q) accO[q] = 0.f;

    const float* Vg = V + (size_t)h * S_ * D_ + lane;

    #pragma unroll 8
    for (int jl = 0; jl < PROWS; ++jl) {       // rows w4 .. w4+135 (132 used; pad rows read p=0)
        const int jj = w4 + jl;
        int gk = k0 + jj;
        gk = gk < 0 ? 0 : (gk > S_ - 1 ? S_ - 1 : gk);
        const float vf = Vg[gk * D_];                     // 256B coalesced per wave
        const float4 pa = psd2[wv * PROWS + jl];          // uniform broadcast read
        accO[0] = fmaf(pa.x, vf, accO[0]);
        accO[1] = fmaf(pa.y, vf, accO[1]);
        accO[2] = fmaf(pa.z, vf, accO[2]);
        accO[3] = fmaf(pa.w, vf, accO[3]);
    }

    float* Og = Out + ((size_t)h * S_ + q0 + w4) * D_ + lane;
    #pragma unroll
    for (int q = 0; q < 4; ++q)
        Og[q * D_] = accO[q] / (l_[q] + 1e-9f);
}

extern "C" void kernel_launch(void* const* d_in, const int* in_sizes, int n_in,
                              void* d_out, int out_size, void* d_ws, size_t ws_size,
                              hipStream_t stream)
{
    const float* Q = (const float*)d_in[0];
    const float* K = (const float*)d_in[1];
    const float* V = (const float*)d_in[2];
    float* Out = (float*)d_out;
    dim3 grid(S_ / TQ, H_);
    swa_fwd<<<grid, 512, 0, stream>>>(Q, K, V, Out);
}